// Round 6
// baseline (347.326 us; speedup 1.0000x reference)
//
#include <hip/hip_runtime.h>
#include <stdint.h>

// SmallMLP: x[65536,784] @ tern(w1[320,784])^T + b1 -> tern -> @ tern(w2[10,320])^T + b2 -> log_softmax
// R9 = R8 resubmit (previous bench died to container infra failure, no kernel verdict;
// deadlock audit found no kernel-side hang cause: barriers uniform, vmcnt can't deadlock,
// no LDS WAR race, ws within bounds).
// R8: kill the LDS bank conflicts + amortize B reads. R7 post-mortem: counted-vmcnt pipeline
// works (122us) but per-chunk LDS cost ~3000 CU-cyc vs MFMA 776: B-frag reads at 64B stride
// were 8-way bank conflicts (8.5M conflict cycles), and 16-row tiles made even conflict-free
// LDS demand (40us) exceed the MFMA floor (32us).
//   - prep_q1 writes W1 in FRAGMENT order (rule #21: permute the global source, gll copies
//     linearly): wave's B-frag read = base + lane*16 -> 1024 contiguous B, conflict-free,
//     zero address math.
//   - 32x80 wave tiles (acc[2][5]=40 regs): B-read cost per MFMA halves -> MFMA-bound.
//   - Counted pipeline kept: LDS double-buffer, gll 1-ahead, A 2-ahead (asm), vmcnt(4)/chunk
//     (stage issued before issueA so newest-4 outstanding are always the A ops).
//   - 1024 blocks x 512 thr = exactly 2 resident blocks/CU, single pass, 16 waves/CU.

#define TERN_TH 0.001f

using bf16x8 = __attribute__((ext_vector_type(8))) short;   // 8 bf16 = 4 VGPR
using f32x4  = __attribute__((ext_vector_type(4))) float;   // 4 fp32 acc
using f32x4v = __attribute__((ext_vector_type(4))) float;

typedef unsigned int u32;
#define AS1 __attribute__((address_space(1)))
#define AS3 __attribute__((address_space(3)))

__device__ __forceinline__ unsigned short f2bf(float f) {
    unsigned u = __float_as_uint(f);
    u = (u + 0x7FFFu + ((u >> 16) & 1u)) >> 16;   // RNE
    return (unsigned short)u;
}
__device__ __forceinline__ float ternf(float w) {
    return (w > TERN_TH) ? 1.0f : ((w < -TERN_TH) ? -1.0f : 0.0f);
}
__device__ __forceinline__ unsigned cvt_pk_bf16(float a, float b) {
    unsigned r;
    asm("v_cvt_pk_bf16_f32 %0, %1, %2" : "=v"(r) : "v"(a), "v"(b));
    return r;
}

// ---------------- prep: ternarize w1 -> bf16 in FRAGMENT layout.
// q1t[c][j2][lane][e]: chunk c (0..24), 16-col block j2 (0..19), lane = quad*16+l15,
// element: col = j2*16 + (lane&15), k = c*32 + (lane>>4)*8 + e.  Total 25*20*64*8 elems.
#define Q1T_ELEMS (25 * 20 * 512)
__global__ void prep_q1(const float* __restrict__ w1, unsigned short* __restrict__ q1t) {
    int idx = blockIdx.x * 256 + threadIdx.x;
    if (idx >= Q1T_ELEMS) return;
    int c  = idx / (20 * 512);
    int r  = idx % (20 * 512);
    int j2 = r / 512;
    int t  = r % 512;
    int l  = t >> 3;
    int e  = t & 7;
    int col = j2 * 16 + (l & 15);
    int k   = c * 32 + ((l >> 4) << 3) + e;
    float v = (k < 784) ? ternf(w1[col * 784 + k]) : 0.0f;
    q1t[idx] = f2bf(v);
}

// ---------------- LDS layout (bytes)
#define BUFB 20480                   // one B buffer: 20 frag-blocks * 1024 B
#define LDS_H  0                     // epilogue: [64][328] bf16 = 41984 (overlaps both buffers)
#define LDS_Q2 41984                 // [16][328] bf16 = 10496 -> 52480
#define LDS_TOTAL 52480

__global__ __launch_bounds__(512, 4) void mlp_main(
    const float* __restrict__ x, const unsigned short* __restrict__ q1t,
    const float* __restrict__ b1, const float* __restrict__ w2,
    const float* __restrict__ b2, float* __restrict__ out) {

    __shared__ __attribute__((aligned(16))) unsigned char smem[LDS_TOTAL];
    unsigned short* sm16 = (unsigned short*)smem;

    const int tid  = threadIdx.x;
    const int lane = tid & 63;
    const int wave = tid >> 6;     // 8 waves
    const int quad = lane >> 4;
    const int l15  = lane & 15;
    const int wm   = wave >> 2;    // 0..1: 32-row group
    const int wn   = wave & 3;     // 0..3: 80-col group
    const int blk  = blockIdx.x;   // 1024 blocks * 64 rows

    f32x4 acc[2][5];
#pragma unroll
    for (int mt = 0; mt < 2; ++mt)
#pragma unroll
        for (int nt = 0; nt < 5; ++nt) {
            f32x4 z = {0.f, 0.f, 0.f, 0.f};
            acc[mt][nt] = z;
        }

    // A rows: blk*64 + wm*32 + mt*16 + l15, k = quad*8..+8
    const float* xr0 = x + (size_t)(blk * 64 + wm * 32 + l15) * 784;       // mt=0
    const float* xr1 = xr0 + (size_t)16 * 784;                             // mt=1
    // per-wave B frag base byte offset inside a buffer: frag-blocks wn*5..wn*5+4
    const int bpoff = wn * 5120 + lane * 16;

    f32x4v raA[4], raB[4];         // [mt*2 + half], 16 VGPR each set
    bf16x8 ahi[2], alo[2];

    // ---- A issue for chunk cc: 4 dwordx4, not waited here (counted by per-chunk vmcnt)
    auto issueA = [&](int cc, f32x4v (&ra)[4]) {
        const float* p0 = xr0 + cc * 32 + quad * 8;
        const float* p1 = xr1 + cc * 32 + quad * 8;
        if (cc == 24 && quad >= 2) { p0 = xr0; p1 = xr1; }   // clamp; zeroed at use
        asm volatile(
            "global_load_dwordx4 %0, %4, off\n\t"
            "global_load_dwordx4 %1, %4, off offset:16\n\t"
            "global_load_dwordx4 %2, %5, off\n\t"
            "global_load_dwordx4 %3, %5, off offset:16"
            : "=&v"(ra[0]), "=&v"(ra[1]), "=&v"(ra[2]), "=&v"(ra[3])
            : "v"(p0), "v"(p1)
            : "memory");
    };
    // ---- B stage chunk c -> buffer: 20 calls of 1024 B (waves 0-3: 3 calls, 4-7: 2)
    auto stageB = [&](int c, int bufoff) {
        const unsigned char* src = (const unsigned char*)q1t + (size_t)c * BUFB;
        unsigned char* dst = smem + bufoff;
#pragma unroll
        for (int i = 0; i < 3; ++i) {
            int call = wave + i * 8;
            if (call < 20)
                __builtin_amdgcn_global_load_lds(
                    (const AS1 u32*)(src + call * 1024 + lane * 16),
                    (AS3 u32*)(dst + call * 1024),
                    16, 0, 0);
        }
    };
    // ---- hi/lo bf16 split in registers
    auto convA = [&](const f32x4v (&ra)[4]) {
#pragma unroll
        for (int mt = 0; mt < 2; ++mt) {
            float v[8] = {ra[mt*2].x, ra[mt*2].y, ra[mt*2].z, ra[mt*2].w,
                          ra[mt*2+1].x, ra[mt*2+1].y, ra[mt*2+1].z, ra[mt*2+1].w};
            union { unsigned w[4]; bf16x8 b; } uh, ul;
#pragma unroll
            for (int i = 0; i < 4; ++i) {
                unsigned hp = cvt_pk_bf16(v[2 * i], v[2 * i + 1]);
                float h0 = __uint_as_float(hp << 16);
                float h1 = __uint_as_float(hp & 0xffff0000u);
                uh.w[i] = hp;
                ul.w[i] = cvt_pk_bf16(v[2 * i] - h0, v[2 * i + 1] - h1);
            }
            ahi[mt] = uh.b; alo[mt] = ul.b;
        }
    };

    // one chunk body. Per-wave VMEM FIFO at top of body c (oldest->newest):
    // [A(c) already certified] gll(c) ... A(c+1) x4 (or gll(c+1)+A(c+2) in steady state
    // ordering stageB-then-issueA) -> vmcnt(4) leaves the newest 4 (the last issueA)
    // outstanding and certifies gll(c)+A(c). Raw s_barrier (no implicit drain) publishes
    // gll(c) writes block-wide; prior-buffer reads completed before each wave's MFMAs.
    auto body = [&](int c, f32x4v (&ra)[4], bool fin) {
        if (fin) { asm volatile("s_waitcnt vmcnt(0)" ::: "memory"); }
        else     { asm volatile("s_waitcnt vmcnt(4)" ::: "memory"); }
        __builtin_amdgcn_sched_barrier(0);
        __builtin_amdgcn_s_barrier();
        __builtin_amdgcn_sched_barrier(0);
        if (fin && quad >= 2) {            // zero clamped tail lanes (k 784..799)
            f32x4v z = {0.f, 0.f, 0.f, 0.f};
            ra[0] = z; ra[1] = z; ra[2] = z; ra[3] = z;
        }
        convA(ra);
        if (c < 24) stageB(c + 1, (c & 1) ? 0 : BUFB);   // fills the buffer freed at this barrier
        if (c < 23) issueA(c + 2, ra);                   // same slot; convA already consumed it
        __builtin_amdgcn_sched_barrier(0);
        const unsigned char* bp = smem + ((c & 1) ? BUFB : 0) + bpoff;
#pragma unroll
        for (int nt = 0; nt < 5; ++nt) {
            union { uint4 u; bf16x8 b; } cb;
            cb.u = *(const uint4*)(bp + nt * 1024);      // contiguous 1024B/wave: conflict-free
            acc[0][nt] = __builtin_amdgcn_mfma_f32_16x16x32_bf16(ahi[0], cb.b, acc[0][nt], 0, 0, 0);
            acc[0][nt] = __builtin_amdgcn_mfma_f32_16x16x32_bf16(alo[0], cb.b, acc[0][nt], 0, 0, 0);
            acc[1][nt] = __builtin_amdgcn_mfma_f32_16x16x32_bf16(ahi[1], cb.b, acc[1][nt], 0, 0, 0);
            acc[1][nt] = __builtin_amdgcn_mfma_f32_16x16x32_bf16(alo[1], cb.b, acc[1][nt], 0, 0, 0);
        }
    };

    // ---- prologue: FIFO [gll0, A0 x4, A1 x4] -> body0's vmcnt(4) waits gll0+A0, leaves A1
    stageB(0, 0);
    issueA(0, raA);
    issueA(1, raB);

    // ---- main loop: chunks 0..23 in pairs (static slot names), chunk 24 tail
#pragma unroll 1
    for (int cp = 0; cp < 12; ++cp) {
        body(2 * cp,     raA, false);
        body(2 * cp + 1, raB, false);
    }
    body(24, raA, true);

    // ---------------- fused epilogue (layer 2 + log_softmax)
    __syncthreads();   // full drain once; LDS reused for H/Q2
    float b1v[5];
#pragma unroll
    for (int nt = 0; nt < 5; ++nt) b1v[nt] = b1[wn * 80 + nt * 16 + l15];
    // write ternarized h (bf16) to LDS H[64][328]
#pragma unroll
    for (int mt = 0; mt < 2; ++mt)
#pragma unroll
        for (int nt = 0; nt < 5; ++nt)
#pragma unroll
            for (int i = 0; i < 4; ++i) {
                float hv = acc[mt][nt][i] + b1v[nt];
                int row = wm * 32 + mt * 16 + quad * 4 + i;   // C layout: col=l15, row=quad*4+reg
                int col = wn * 80 + nt * 16 + l15;
                sm16[(LDS_H >> 1) + row * 328 + col] = f2bf(ternf(hv));
            }
    // stage q2: tern(w2) -> bf16 [16][328], rows 10..15 and cols 320..327 zero
    for (int idx = tid; idx < 16 * 328; idx += 512) {
        int o = idx / 328, j = idx % 328;
        float v = (o < 10 && j < 320) ? ternf(w2[o * 320 + j]) : 0.0f;
        sm16[(LDS_Q2 >> 1) + idx] = f2bf(v);
    }
    __syncthreads();
    // layer 2: waves 0..3 compute 16 rows x 16 cols (10 valid), K=320
    if (wave < 4) {
        float b2v = (l15 < 10) ? b2[l15] : 0.0f;
        f32x4 acc2 = {0.f, 0.f, 0.f, 0.f};
#pragma unroll
        for (int kc = 0; kc < 10; ++kc) {
            bf16x8 a = *(const bf16x8*)(smem + LDS_H + (wave * 16 + l15) * 656 + kc * 64 + quad * 16);
            bf16x8 b = *(const bf16x8*)(smem + LDS_Q2 + l15 * 656 + kc * 64 + quad * 16);
            acc2 = __builtin_amdgcn_mfma_f32_16x16x32_bf16(a, b, acc2, 0, 0, 0);
        }
        // log_softmax across the 16 lanes holding one row (cols), 10 valid
#pragma unroll
        for (int i = 0; i < 4; ++i) {
            float l  = acc2[i] + b2v;
            float lm = (l15 < 10) ? l : -3.4e38f;
#pragma unroll
            for (int s = 8; s >= 1; s >>= 1) lm = fmaxf(lm, __shfl_xor(lm, s, 64));
            float e  = (l15 < 10) ? expf(l - lm) : 0.0f;
            float ss = e;
#pragma unroll
            for (int s = 8; s >= 1; s >>= 1) ss += __shfl_xor(ss, s, 64);
            float ov = (l - lm) - logf(ss);
            if (l15 < 10) {
                int grow = blk * 64 + wave * 16 + quad * 4 + i;
                out[(size_t)grow * 10 + l15] = ov;
            }
        }
    }
}

extern "C" void kernel_launch(void* const* d_in, const int* in_sizes, int n_in,
                              void* d_out, int out_size, void* d_ws, size_t ws_size,
                              hipStream_t stream) {
    const float* x  = (const float*)d_in[0];
    const float* w1 = (const float*)d_in[1];
    const float* b1 = (const float*)d_in[2];
    const float* w2 = (const float*)d_in[3];
    const float* b2 = (const float*)d_in[4];
    unsigned short* q1t = (unsigned short*)d_ws;   // 512000 B

    prep_q1<<<(Q1T_ELEMS + 255) / 256, 256, 0, stream>>>(w1, q1t);
    mlp_main<<<1024, 512, 0, stream>>>(x, q1t, b1, w2, b2, (float*)d_out);
}